// Round 1
// 209.569 us; speedup vs baseline: 1.0003x; 1.0003x over previous
//
#include <hip/hip_runtime.h>

namespace {
constexpr int TOK = 8192;
constexpr int DIM = 4096;
constexpr int NE  = 64;
constexpr int TB  = 64;           // tokens per tile (16 per wave)
constexpr int NT  = TOK / TB;     // 128 token tiles
constexpr int KS  = 8;            // split-K factor
constexpr int KR  = DIM / KS;     // 512 k per block
constexpr int BK  = 32;           // fp32 k per stage (= one K32 f16 MFMA)
constexpr int NITER = KR / BK;    // 16
constexpr int LSTR = 40;          // LDS row stride in halves
constexpr int GB  = 64;           // tokens per gating chunk
constexpr int NCH = TOK / GB;     // 128 chunks
constexpr int FB  = 32;           // finalize blocks (4 chunks / 256 tokens each)
}

typedef _Float16 f16x8 __attribute__((ext_vector_type(8)));
typedef _Float16 f16x4 __attribute__((ext_vector_type(4)));
typedef float    f32x4 __attribute__((ext_vector_type(4)));

// ---------------------------------------------------------------------------
// Split-K GEMM, fp16x2-split MFMA (Ahi*Bhi + Ahi*Blo + Alo*Bhi).
// A: global -> registers directly (zero block-level reuse, so no LDS staging).
// W: double-buffered LDS, converted once per 32-k chunk. One barrier / K-step.
// 1024 blocks x 256 threads; wave w owns tokens [t0+16w, t0+16w+16) x 64 experts.
// ---------------------------------------------------------------------------
__global__ __launch_bounds__(256, 4) void gemm_split(
    const float* __restrict__ A, const float* __restrict__ W,
    float* __restrict__ partial) {
  __shared__ _Float16 sw[2][2][NE * LSTR];   // [buf][hi/lo], 20 KB

  const int bid  = blockIdx.x;
  const int tile = bid & (NT - 1);
  const int ks   = bid >> 7;                 // bid / NT
  const int t0   = tile * TB;
  const int k0   = ks * KR;
  const int tid  = threadIdx.x;
  const int w    = tid >> 6;
  const int lane = tid & 63;
  const int col  = lane & 15;                // MFMA m (A row) / n (B col) low bits
  const int quad = lane >> 4;                // k chunk + C row group

  // A-fragment source: lane (col,quad) reads 8 contiguous floats of its row.
  const float* Ap = A + (size_t)(t0 + w * 16 + col) * DIM + k0 + quad * 8;
  // W staging: 512 float4 = 64 experts x 32 k per chunk, 2 per thread.
  const int e0  = tid >> 3,          kc0 = (tid & 7) * 4;
  const int e1  = (tid + 256) >> 3,  kc1 = kc0;
  const float* Wp0 = W + (size_t)e0 * DIM + k0 + kc0;
  const float* Wp1 = W + (size_t)e1 * DIM + k0 + kc1;

  // prologue: A regs for it=0, W chunk 0 -> buf 0
  float4 a0 = *(const float4*)(Ap);
  float4 a1 = *(const float4*)(Ap + 4);
  {
    const float4 r0 = *(const float4*)Wp0;
    const float4 r1 = *(const float4*)Wp1;
    const _Float16 ax=(_Float16)r0.x, ay=(_Float16)r0.y, az=(_Float16)r0.z, aw=(_Float16)r0.w;
    *(f16x4*)(&sw[0][0][e0*LSTR+kc0]) = (f16x4){ax,ay,az,aw};
    *(f16x4*)(&sw[0][1][e0*LSTR+kc0]) =
        (f16x4){(_Float16)(r0.x-(float)ax),(_Float16)(r0.y-(float)ay),
                (_Float16)(r0.z-(float)az),(_Float16)(r0.w-(float)aw)};
    const _Float16 bx=(_Float16)r1.x, by=(_Float16)r1.y, bz=(_Float16)r1.z, bw=(_Float16)r1.w;
    *(f16x4*)(&sw[0][0][e1*LSTR+kc1]) = (f16x4){bx,by,bz,bw};
    *(f16x4*)(&sw[0][1][e1*LSTR+kc1]) =
        (f16x4){(_Float16)(r1.x-(float)bx),(_Float16)(r1.y-(float)by),
                (_Float16)(r1.z-(float)bz),(_Float16)(r1.w-(float)bw)};
  }
  __syncthreads();

  f32x4 acc[4];
#pragma unroll
  for (int j = 0; j < 4; ++j) acc[j] = (f32x4)0.0f;

  for (int it = 0; it < NITER; ++it) {
    const int cur = it & 1;
    float4 an0, an1, wn0, wn1;
    if (it + 1 < NITER) {     // prefetch next chunk (A regs + W regs)
      const int kb = (it + 1) * BK;
      an0 = *(const float4*)(Ap + kb);
      an1 = *(const float4*)(Ap + kb + 4);
      wn0 = *(const float4*)(Wp0 + kb);
      wn1 = *(const float4*)(Wp1 + kb);
    }
    // convert current A regs -> hi/lo f16 fragments (no LDS round trip)
    f16x8 ah, al;
    {
      const _Float16 h0=(_Float16)a0.x,h1=(_Float16)a0.y,h2=(_Float16)a0.z,h3=(_Float16)a0.w;
      const _Float16 h4=(_Float16)a1.x,h5=(_Float16)a1.y,h6=(_Float16)a1.z,h7=(_Float16)a1.w;
      ah = (f16x8){h0,h1,h2,h3,h4,h5,h6,h7};
      al = (f16x8){(_Float16)(a0.x-(float)h0),(_Float16)(a0.y-(float)h1),
                   (_Float16)(a0.z-(float)h2),(_Float16)(a0.w-(float)h3),
                   (_Float16)(a1.x-(float)h4),(_Float16)(a1.y-(float)h5),
                   (_Float16)(a1.z-(float)h6),(_Float16)(a1.w-(float)h7)};
    }
    f16x8 bh[4], bl[4];
#pragma unroll
    for (int et = 0; et < 4; ++et) {
      const int off = (et * 16 + col) * LSTR + quad * 8;
      bh[et] = *(const f16x8*)(&sw[cur][0][off]);
      bl[et] = *(const f16x8*)(&sw[cur][1][off]);
    }
#pragma unroll
    for (int et = 0; et < 4; ++et) {
      acc[et] = __builtin_amdgcn_mfma_f32_16x16x32_f16(ah, bh[et], acc[et], 0, 0, 0);
      acc[et] = __builtin_amdgcn_mfma_f32_16x16x32_f16(ah, bl[et], acc[et], 0, 0, 0);
      acc[et] = __builtin_amdgcn_mfma_f32_16x16x32_f16(al, bh[et], acc[et], 0, 0, 0);
    }
    if (it + 1 < NITER) {     // stage next W chunk into the other buffer
      const int nxt = cur ^ 1;
      const _Float16 ax=(_Float16)wn0.x, ay=(_Float16)wn0.y, az=(_Float16)wn0.z, aw=(_Float16)wn0.w;
      *(f16x4*)(&sw[nxt][0][e0*LSTR+kc0]) = (f16x4){ax,ay,az,aw};
      *(f16x4*)(&sw[nxt][1][e0*LSTR+kc0]) =
          (f16x4){(_Float16)(wn0.x-(float)ax),(_Float16)(wn0.y-(float)ay),
                  (_Float16)(wn0.z-(float)az),(_Float16)(wn0.w-(float)aw)};
      const _Float16 bx=(_Float16)wn1.x, by=(_Float16)wn1.y, bz=(_Float16)wn1.z, bw=(_Float16)wn1.w;
      *(f16x4*)(&sw[nxt][0][e1*LSTR+kc1]) = (f16x4){bx,by,bz,bw};
      *(f16x4*)(&sw[nxt][1][e1*LSTR+kc1]) =
          (f16x4){(_Float16)(wn1.x-(float)bx),(_Float16)(wn1.y-(float)by),
                  (_Float16)(wn1.z-(float)bz),(_Float16)(wn1.w-(float)bw)};
      a0 = an0; a1 = an1;
      __syncthreads();
    }
  }

  // epilogue: C/D layout col=lane&15 (expert), row=quad*4+r (token)
  float* P = partial + (size_t)ks * TOK * NE;
  const int trow = t0 + w * 16 + quad * 4;
#pragma unroll
  for (int et = 0; et < 4; ++et) {
    const int e = et * 16 + col;
#pragma unroll
    for (int r = 0; r < 4; ++r)
      P[(size_t)(trow + r) * NE + e] = acc[et][r];
  }
}

// ---------------------------------------------------------------------------
// Gating: float4 partial reduce -> logits in LDS; argmax/softmax/me/hist all
// parallelized 4-way across the 256 threads (partition + combine); exp
// computed once, stored in place.
// ---------------------------------------------------------------------------
__global__ __launch_bounds__(256) void gating(
    const float* __restrict__ partial, float* __restrict__ out,
    int* __restrict__ idx_int, int* __restrict__ rankp,
    int* __restrict__ hist, float* __restrict__ me_part) {
  __shared__ float L[GB * 65];      // logits, then gates (exp) in place
  __shared__ float redf[4 * GB];
  __shared__ int   redi[4 * GB];
  __shared__ float mx[GB], dninv[GB];
  __shared__ int   eid[GB];
  const int b = blockIdx.x, tid = threadIdx.x;
  const int p = tid >> 6, l = tid & 63;

  // 1) sum KS split-K partials, float4-vectorized global loads
  const float4* P4 = (const float4*)partial;
  const int base4 = b * (GB * NE / 4);
#pragma unroll
  for (int j = 0; j < 4; ++j) {
    const int v4 = tid + 256 * j;
    float sx = 0.f, sy = 0.f, sz = 0.f, sww = 0.f;
#pragma unroll
    for (int k = 0; k < KS; ++k) {
      const float4 v = P4[(size_t)k * (TOK * NE / 4) + base4 + v4];
      sx += v.x; sy += v.y; sz += v.z; sww += v.w;
    }
    const int t = v4 >> 4, c4 = v4 & 15;
    float* row = &L[t * 65 + c4 * 4];
    row[0] = sx; row[1] = sy; row[2] = sz; row[3] = sww;
  }
  __syncthreads();

  // 2) argmax: thread (t=l, part=p) scans 16 experts; first-occurrence ties
  {
    float m = -3.0e38f; int bi = 0;
    for (int e = p * 16; e < p * 16 + 16; ++e) {
      const float v = L[l * 65 + e];
      if (v > m) { m = v; bi = e; }
    }
    redf[p * GB + l] = m; redi[p * GB + l] = bi;
  }
  __syncthreads();
  if (tid < GB) {
    float m = redf[tid]; int bi = redi[tid];
#pragma unroll
    for (int q = 1; q < 4; ++q) {
      const float v = redf[q * GB + tid];
      if (v > m) { m = v; bi = redi[q * GB + tid]; }
    }
    mx[tid] = m; eid[tid] = bi;
  }
  __syncthreads();

  // 3) exp once, in place; partial denominators
  {
    const float m = mx[l];
    float s = 0.0f;
    for (int e = p * 16; e < p * 16 + 16; ++e) {
      const float g = __expf(L[l * 65 + e] - m);
      L[l * 65 + e] = g; s += g;
    }
    redf[p * GB + l] = s;
  }
  __syncthreads();
  if (tid < GB) {
    const float inv = 1.0f / (redf[tid] + redf[GB + tid] + redf[2 * GB + tid] + redf[3 * GB + tid]);
    dninv[tid] = inv;
    const int gt = b * GB + tid;
    out[1 + gt]           = (float)eid[tid];   // indices1_s
    out[1 + 2 * TOK + gt] = inv;               // gates1_s (prob at argmax)
    idx_int[gt] = eid[tid];
  }
  __syncthreads();

  // 4+5) me partials + hist partials: thread (e=l, part=p) over 16 tokens
  {
    float s = 0.0f; int c = 0;
    for (int t2 = p * 16; t2 < p * 16 + 16; ++t2) {
      s += L[t2 * 65 + l] * dninv[t2];
      c += (eid[t2] == l) ? 1 : 0;
    }
    redf[p * GB + l] = s; redi[p * GB + l] = c;
  }
  __syncthreads();
  if (tid < GB) {
    me_part[b * NE + tid] = redf[tid] + redf[GB + tid] + redf[2 * GB + tid] + redf[3 * GB + tid];
    hist[b * NE + tid]    = redi[tid] + redi[GB + tid] + redi[2 * GB + tid] + redi[3 * GB + tid];
    // within-chunk rank (serial but cheap: LDS broadcast reads)
    const int e = eid[tid];
    int r = 0;
    for (int j = 0; j < tid; ++j) r += (eid[j] == e) ? 1 : 0;
    rankp[b * GB + tid] = r;
  }
}

// ---------------------------------------------------------------------------
// Finalize: 32 blocks. Each redundantly computes the cheap segment scan, then
// writes locations for its own 4 chunks (256 tokens). Block 0 computes l_aux.
// ---------------------------------------------------------------------------
__global__ __launch_bounds__(256) void finalize(
    const int* __restrict__ idx_int, const int* __restrict__ rankp,
    const int* __restrict__ hist, const float* __restrict__ me_part,
    float* __restrict__ out) {
  __shared__ int   H[NCH * NE];     // 32 KB
  __shared__ int   SEG[4 * NE];
  __shared__ float CE[NE];
  __shared__ int   LOC[4 * NE];
  __shared__ float MEP[4 * NE];
  const int b = blockIdx.x, tid = threadIdx.x;
  const int e = tid & 63, seg = tid >> 6;

  for (int j = tid; j < NCH * NE; j += 256) H[j] = hist[j];
  __syncthreads();
  {
    int hs = 0;
    for (int c = seg * 32; c < seg * 32 + 32; ++c) hs += H[c * NE + e];
    SEG[seg * NE + e] = hs;
  }
  __syncthreads();
  if (tid < NE) {   // exclusive scan of 4 segment sums per expert
    int run = 0;
#pragma unroll
    for (int s2 = 0; s2 < 4; ++s2) {
      const int v = SEG[s2 * NE + tid];
      SEG[s2 * NE + tid] = run;
      run += v;
    }
    CE[tid] = (float)run;          // ce[e]
  }
  __syncthreads();
  {  // exclusive prefix for this block's 4 chunks (c = 4b+seg)
    const int c  = 4 * b + seg;
    const int s0 = c >> 5;
    int run = SEG[s0 * NE + e];
    for (int c2 = s0 * 32; c2 < c; ++c2) run += H[c2 * NE + e];
    LOC[seg * NE + e] = run;
  }
  __syncthreads();
  {  // locations for this block's 256 tokens
    const int i  = b * 256 + tid;
    const int ex = idx_int[i];
    out[1 + TOK + i] = (float)(LOC[(tid >> 6) * NE + ex] + rankp[i]);
  }
  if (b == 0) {  // l_aux
    float s = 0.0f;
    for (int c = seg * 32; c < seg * 32 + 32; ++c) s += me_part[c * NE + e];
    MEP[seg * NE + e] = s;
    __syncthreads();
    if (tid < NE) {
      float pv = (MEP[tid] + MEP[NE + tid] + MEP[2 * NE + tid] + MEP[3 * NE + tid]) * CE[tid];
#pragma unroll
      for (int off = 32; off > 0; off >>= 1) pv += __shfl_down(pv, off);
      if (tid == 0) out[0] = pv * ((float)NE / ((float)TOK * (float)TOK));
    }
  }
}

extern "C" void kernel_launch(void* const* d_in, const int* in_sizes, int n_in,
                              void* d_out, int out_size, void* d_ws, size_t ws_size,
                              hipStream_t stream) {
  const float* A = (const float*)d_in[0];   // [8192, 4096] fp32
  const float* W = (const float*)d_in[1];   // [64, 4096] fp32
  float* out = (float*)d_out;               // 1 + 8192*3 floats
  char* ws = (char*)d_ws;

  float* partial = (float*)ws;                                  // 16 MB
  const size_t poff = (size_t)KS * TOK * NE * sizeof(float);
  float* me_part = (float*)(ws + poff);                         // NCH*NE floats
  int*  idx_int = (int*)(ws + poff + NCH * NE * sizeof(float));
  int*  rankp   = idx_int + TOK;
  int*  hist    = rankp + TOK;

  hipLaunchKernelGGL(gemm_split, dim3(NT * KS), dim3(256), 0, stream, A, W, partial);
  hipLaunchKernelGGL(gating, dim3(NCH), dim3(256), 0, stream, partial, out,
                     idx_int, rankp, hist, me_part);
  hipLaunchKernelGGL(finalize, dim3(FB), dim3(256), 0, stream, idx_int, rankp,
                     hist, me_part, out);
}